// Round 10
// baseline (217.464 us; speedup 1.0000x reference)
//
#include <hip/hip_runtime.h>

// MHA forward: inputs fp32, output fp32. Internals bf16 MFMA.
// (0) cvt fp32->bf16, (1) QKV gemm (BK=64, XOR-swizzled LDS, global_load_lds;
// V written TRANSPOSED [hd][m]; Q pre-scaled by 0.125*log2e), (2) causal
// flash-attention (S^T/O^T, exp2 softmax, all-gll16 staging, swizzled LDS),
// (3) O-proj gemm -> fp32.

#define DMODEL 1024
#define NHEADS 16
#define DHEAD  64
#define SEQ    2048
#define BATCH  2
#define MROWS  (BATCH * SEQ)   // 4096

typedef __bf16 bf16x8 __attribute__((ext_vector_type(8)));
typedef __bf16 bf16x4 __attribute__((ext_vector_type(4)));
typedef float  f32x4  __attribute__((ext_vector_type(4)));

__device__ __forceinline__ f32x4 mfma16(bf16x8 a, bf16x8 b, f32x4 c) {
    return __builtin_amdgcn_mfma_f32_16x16x32_bf16(a, b, c, 0, 0, 0);
}

__device__ __forceinline__ bf16x8 ld8(const float* p) {
    const f32x4 a0 = *(const f32x4*)p;
    const f32x4 a1 = *(const f32x4*)(p + 4);
    bf16x8 v;
    v[0] = (__bf16)a0[0]; v[1] = (__bf16)a0[1];
    v[2] = (__bf16)a0[2]; v[3] = (__bf16)a0[3];
    v[4] = (__bf16)a1[0]; v[5] = (__bf16)a1[1];
    v[6] = (__bf16)a1[2]; v[7] = (__bf16)a1[3];
    return v;
}

// async global->LDS, 16 B/lane; LDS dest = wave-uniform base + lane*16
__device__ __forceinline__ void gll16(const __bf16* g, __bf16* l) {
    __builtin_amdgcn_global_load_lds(
        (const __attribute__((address_space(1))) void*)g,
        (__attribute__((address_space(3))) void*)l,
        16, 0, 0);
}

// ---------------------------------------------------------------------------
// fp32 -> bf16 conversion pass. y=0: x; y=1..4: W's -> wcat.
// ---------------------------------------------------------------------------
__global__ __launch_bounds__(256) void cvt_kernel(const float* __restrict__ x,
                                                  const float* __restrict__ Wq,
                                                  const float* __restrict__ Wk,
                                                  const float* __restrict__ Wv,
                                                  const float* __restrict__ Wo,
                                                  __bf16* __restrict__ xb,
                                                  __bf16* __restrict__ wcat) {
    const int y = blockIdx.y;
    const float* src;
    __bf16* dst;
    int nchunks;
    if (y == 0) { src = x; dst = xb; nchunks = (MROWS * DMODEL) / 8; }
    else {
        src = (y == 1) ? Wq : (y == 2) ? Wk : (y == 3) ? Wv : Wo;
        dst = wcat + (size_t)(y - 1) * DMODEL * DMODEL;
        nchunks = (DMODEL * DMODEL) / 8;
    }
    const int c = blockIdx.x * 256 + threadIdx.x;
    if (c < nchunks) *(bf16x8*)(dst + (size_t)c * 8) = ld8(src + (size_t)c * 8);
}

// ---------------------------------------------------------------------------
// Pure-bf16 GEMM, BK=64, 128x128 tile, 256 threads.
// LDS XOR swizzle: LDS[row][g] = Glb[row][g ^ (row&7)] (granule = 8 elems),
// staged via global_load_lds (lane l: row += l>>3, granule (l&7)^(l>>3)).
// Fragment b128 reads then land 2-way-conflict-free (free per m136).
// Epilogue: normal C[m][n], or (vt) transposed VT[n][m] via b64 stores.
// ---------------------------------------------------------------------------
template <typename TC>
__device__ __forceinline__ void gemm_bb_body(const __bf16* __restrict__ A,
                                             const __bf16* __restrict__ W,
                                             TC* __restrict__ C,
                                             __bf16* __restrict__ VT,
                                             bool vt, int m0, int n0,
                                             float scale) {
    constexpr int K = DMODEL;
    __shared__ __align__(16) __bf16 As[128][64];  // 16 KB, swizzled
    __shared__ __align__(16) __bf16 Bs[128][64];

    const int tid  = threadIdx.x;
    const int lane = tid & 63;
    const int wave = tid >> 6;
    const int quad = lane >> 4;
    const int l16  = lane & 15;
    const int wm   = wave & 1;
    const int wn   = wave >> 1;

    // staging source: lane l -> row_local l>>3, src granule (l&7)^(l>>3)
    const int sr = lane >> 3;                 // 0..7
    const int sc = ((lane & 7) ^ sr) * 8;     // swizzled source col

    f32x4 acc[4][4] = {};

    for (int k0 = 0; k0 < K; k0 += 64) {
        __syncthreads();
#pragma unroll
        for (int s = 0; s < 4; ++s) {
            const int row = s * 32 + wave * 8 + sr;
            gll16(A + (size_t)(m0 + row) * K + k0 + sc, &As[s * 32 + wave * 8][0]);
            gll16(W + (size_t)(n0 + row) * K + k0 + sc, &Bs[s * 32 + wave * 8][0]);
        }
        __syncthreads();   // drains vmcnt before LDS reads

#pragma unroll
        for (int h = 0; h < 2; ++h) {
            bf16x8 af[4], bfr[4];
#pragma unroll
            for (int i = 0; i < 4; ++i) {
                const int gr = ((h * 4 + quad) ^ (l16 & 7)) * 8;
                af[i]  = *(const bf16x8*)(&As[wm * 64 + i * 16 + l16][gr]);
                bfr[i] = *(const bf16x8*)(&Bs[wn * 64 + i * 16 + l16][gr]);
            }
#pragma unroll
            for (int mi = 0; mi < 4; ++mi)
#pragma unroll
                for (int ni = 0; ni < 4; ++ni)
                    acc[mi][ni] = mfma16(af[mi], bfr[ni], acc[mi][ni]);
        }
    }

    // C/D layout: col = l16, row = quad*4 + r
    if (!vt) {
#pragma unroll
        for (int mi = 0; mi < 4; ++mi)
#pragma unroll
            for (int ni = 0; ni < 4; ++ni)
#pragma unroll
                for (int r = 0; r < 4; ++r) {
                    int row = m0 + wm * 64 + mi * 16 + quad * 4 + r;
                    int col = n0 + wn * 64 + ni * 16 + l16;
                    C[(size_t)row * DMODEL + col] = (TC)(acc[mi][ni][r] * scale);
                }
    } else {
        // transposed store: VT[hd][m]; lane holds 4 consecutive m -> b64
#pragma unroll
        for (int mi = 0; mi < 4; ++mi)
#pragma unroll
            for (int ni = 0; ni < 4; ++ni) {
                const int m  = m0 + wm * 64 + mi * 16 + quad * 4;
                const int hd = n0 + wn * 64 + ni * 16 + l16;
                bf16x4 v4;
#pragma unroll
                for (int r = 0; r < 4; ++r) v4[r] = (__bf16)acc[mi][ni][r];
                *(bf16x4*)(VT + (size_t)hd * MROWS + m) = v4;
            }
    }
}

// Q pre-scale: 1/sqrt(Dh) * log2(e) so attention scores are log2-domain.
#define QSCALE 0.1803368801111204f

__global__ __launch_bounds__(256) void qkv_kernel(const __bf16* __restrict__ X,
                                                  const __bf16* __restrict__ wcat,
                                                  __bf16* __restrict__ Q,
                                                  __bf16* __restrict__ K,
                                                  __bf16* __restrict__ VT) {
    const int z = blockIdx.z;
    const __bf16* W = wcat + (size_t)z * DMODEL * DMODEL;
    __bf16* Y = (z == 0) ? Q : K;   // z==2 uses VT path
    const float scale = (z == 0) ? QSCALE : 1.0f;
    gemm_bb_body<__bf16>(X, W, Y, VT, z == 2,
                         blockIdx.y * 128, blockIdx.x * 128, scale);
}

__global__ __launch_bounds__(256) void out_gemm_kernel(const __bf16* __restrict__ A,
                                                       const __bf16* __restrict__ W,
                                                       float* __restrict__ C) {
    gemm_bb_body<float>(A, W, C, nullptr, false,
                        blockIdx.y * 128, blockIdx.x * 128, 1.0f);
}

// ---------------------------------------------------------------------------
// Causal flash attention, S^T / O^T, exp2 softmax, unpaired grid.
// Block = 128 threads (2 waves x 16 q). Grid (bh 32, y 64), qt = 63-y.
// K staged [kk 32][d 64] and V^T staged [dh 64][kk 32], both via gll16 with
// XOR-granule source swizzle (Ks: g^=row&7; Vs: g^=(row>>1)&3) so all b128
// fragment reads are 2-way-conflict-free. No LDS write instructions remain
// in the staging path.
// ---------------------------------------------------------------------------
__global__ __launch_bounds__(128) void attn_kernel(const __bf16* __restrict__ Q,
                                                   const __bf16* __restrict__ Kg,
                                                   const __bf16* __restrict__ VTg,
                                                   __bf16* __restrict__ O) {
    const int bh = blockIdx.x;        // 0..31 (fast dim -> XCD affinity)
    const int qt = 63 - blockIdx.y;   // 0..63, biggest tiles first
    const int b = bh >> 4, h = bh & 15;
    const size_t base = (size_t)b * SEQ * DMODEL + (size_t)h * DHEAD;

    const int tid  = threadIdx.x;
    const int lane = tid & 63;
    const int wave = tid >> 6;
    const int quad = lane >> 4;
    const int l16  = lane & 15;

    __shared__ __align__(16) __bf16 Ks[32][64];     // [kk][d], swizzled g^=row&7
    __shared__ __align__(16) __bf16 Vs[64][32];     // [dh][kk], swizzled g^=(row>>1)&3
    __shared__ __align__(16) __bf16 Ps[2][16][40];  // per-wave [q][kk]

    // Ks staging: lane l -> row_local l>>3, src d-col ((l&7)^(l>>3))*8
    const int ksr = lane >> 3;                  // 0..7
    const int ksc = ((lane & 7) ^ ksr) * 8;
    // Vs staging: lane l -> row_local l>>2, src kk-col ((l&3)^((l>>3)&3))*8
    const int vsr = lane >> 2;                  // 0..15
    const int vsc = ((lane & 3) ^ ((lane >> 3) & 3)) * 8;

    const int qrow = qt * 32 + wave * 16 + l16;

    // Q fragments (already scaled by 0.125*log2e at QKV epilogue)
    const bf16x8 qf0 = *(const bf16x8*)(Q + base + (size_t)qrow * DMODEL + quad * 8);
    const bf16x8 qf1 = *(const bf16x8*)(Q + base + (size_t)qrow * DMODEL + 32 + quad * 8);

    f32x4 oacc[4] = {};
    float m_i = -1e30f, l_i = 0.f;

    for (int kt = 0; kt <= qt; ++kt) {
        const int k0 = kt * 32;
        __syncthreads();   // previous tile's reads done
#pragma unroll
        for (int j = 0; j < 2; ++j) {
            // K rows: wave*16 + j*8 + (l>>3)
            gll16(Kg + base + (size_t)(k0 + wave * 16 + j * 8 + ksr) * DMODEL + ksc,
                  &Ks[wave * 16 + j * 8][0]);
            // V^T rows (dh): j*32 + wave*16 + (l>>2); cols kk
            gll16(VTg + (size_t)(h * 64 + j * 32 + wave * 16 + vsr) * MROWS
                      + (size_t)b * SEQ + k0 + vsc,
                  &Vs[j * 32 + wave * 16][0]);
        }
        __syncthreads();   // vmcnt drained before LDS reads

        const bool diag = (kt == qt);   // wave-uniform

        // S^T[kk][q] (log2 domain): A = K rows, B = Q^T.
        // Swizzled read: granule (h4+quad)^(l16&7) for rows l16 / 16+l16.
        const int g0 = ((quad ^ (l16 & 7))) * 8;
        const int g1 = ((quad ^ 4) ^ (l16 & 7)) * 8;
        const bf16x8 kf00 = *(const bf16x8*)(&Ks[l16][g0]);
        const bf16x8 kf01 = *(const bf16x8*)(&Ks[l16][g1]);
        const bf16x8 kf10 = *(const bf16x8*)(&Ks[16 + l16][g0]);
        const bf16x8 kf11 = *(const bf16x8*)(&Ks[16 + l16][g1]);
        f32x4 s0 = {}, s1 = {};
        s0 = mfma16(kf00, qf0, s0); s0 = mfma16(kf01, qf1, s0);
        s1 = mfma16(kf10, qf0, s1); s1 = mfma16(kf11, qf1, s1);

        float mx;
        bool ok[2][4];
        if (!diag) {
            float m0 = s0[0];
#pragma unroll
            for (int r = 1; r < 4; ++r) m0 = fmaxf(m0, s0[r]);
#pragma unroll
            for (int r = 0; r < 4; ++r) m0 = fmaxf(m0, s1[r]);
            mx = m0;
        } else {
            mx = -1e30f;
#pragma unroll
            for (int hh = 0; hh < 2; ++hh)
#pragma unroll
                for (int r = 0; r < 4; ++r) {
                    const int kk = k0 + hh * 16 + quad * 4 + r;
                    ok[hh][r] = (kk <= qrow);
                    const float v = hh ? s1[r] : s0[r];
                    mx = fmaxf(mx, ok[hh][r] ? v : -1e30f);
                }
        }
        mx = fmaxf(mx, __shfl_xor(mx, 16));
        mx = fmaxf(mx, __shfl_xor(mx, 32));
        const float mnew  = fmaxf(m_i, mx);
        const float alpha = exp2f(m_i - mnew);
        m_i = mnew;

        float p[2][4];
        float rs = 0.f;
        if (!diag) {
#pragma unroll
            for (int hh = 0; hh < 2; ++hh)
#pragma unroll
                for (int r = 0; r < 4; ++r) {
                    p[hh][r] = exp2f((hh ? s1[r] : s0[r]) - mnew);
                    rs += p[hh][r];
                }
        } else {
#pragma unroll
            for (int hh = 0; hh < 2; ++hh)
#pragma unroll
                for (int r = 0; r < 4; ++r) {
                    p[hh][r] = ok[hh][r] ? exp2f((hh ? s1[r] : s0[r]) - mnew) : 0.f;
                    rs += p[hh][r];
                }
        }
        rs += __shfl_xor(rs, 16);
        rs += __shfl_xor(rs, 32);
        l_i = l_i * alpha + rs;

        bf16x4 w0, w1;
#pragma unroll
        for (int r = 0; r < 4; ++r) { w0[r] = (__bf16)p[0][r]; w1[r] = (__bf16)p[1][r]; }
        *(bf16x4*)(&Ps[wave][l16][quad * 4])      = w0;
        *(bf16x4*)(&Ps[wave][l16][16 + quad * 4]) = w1;

        // O^T += V^T P^T : A = V^T rows from Vs (swizzled), B = P^T
        const bf16x8 pf = *(const bf16x8*)(&Ps[wave][l16][quad * 8]);
        const int vg = (quad ^ ((l16 >> 1) & 3)) * 8;
#pragma unroll
        for (int f = 0; f < 4; ++f) {
            const bf16x8 vf = *(const bf16x8*)(&Vs[f * 16 + l16][vg]);
            oacc[f] = mfma16(vf, pf, oacc[f] * alpha);
        }
    }

    const float inv = (l_i > 0.f) ? (1.f / l_i) : 0.f;
#pragma unroll
    for (int f = 0; f < 4; ++f) {
        bf16x4 o;
#pragma unroll
        for (int r = 0; r < 4; ++r) o[r] = (__bf16)(oacc[f][r] * inv);
        *(bf16x4*)(O + base + (size_t)qrow * DMODEL + f * 16 + quad * 4) = o;
    }
}

// ---------------------------------------------------------------------------
extern "C" void kernel_launch(void* const* d_in, const int* in_sizes, int n_in,
                              void* d_out, int out_size, void* d_ws, size_t ws_size,
                              hipStream_t stream) {
    const float* x  = (const float*)d_in[0];
    const float* Wq = (const float*)d_in[1];
    const float* Wk = (const float*)d_in[2];
    const float* Wv = (const float*)d_in[3];
    const float* Wo = (const float*)d_in[4];
    float* out = (float*)d_out;

    const size_t tm = (size_t)MROWS * DMODEL;    // 4M elems
    const size_t tw = (size_t)DMODEL * DMODEL;   // 1M elems
    __bf16* Q    = (__bf16*)d_ws;                // 4M
    __bf16* K    = Q + tm;                       // 4M
    __bf16* VT   = K + tm;                       // 4M  (V transposed [hd][m])
    __bf16* xb   = VT + tm;                      // 4M
    __bf16* wcat = xb + tm;                      // 4M (Wq,Wk,Wv,Wo)  -> 40 MB

    dim3 gc(2048, 5);
    cvt_kernel<<<gc, 256, 0, stream>>>(x, Wq, Wk, Wv, Wo, xb, wcat);

    dim3 g1(DMODEL / 128, MROWS / 128, 3);
    qkv_kernel<<<g1, 256, 0, stream>>>(xb, wcat, Q, K, VT);

    dim3 g2(BATCH * NHEADS, SEQ / 32);           // (bh, y): qt = 63 - y
    attn_kernel<<<g2, 128, 0, stream>>>(Q, K, VT, /*O=*/Q);

    dim3 g3(DMODEL / 128, MROWS / 128);
    out_gemm_kernel<<<g3, 256, 0, stream>>>(/*O=*/Q, wcat + 3 * tw, out);
}

// Round 11
// 194.490 us; speedup vs baseline: 1.1181x; 1.1181x over previous
//
#include <hip/hip_runtime.h>

// MHA forward: inputs fp32, output fp32. Internals bf16 MFMA.
// (0) cvt fp32->bf16, (1) QKV gemm (round-9 BK=32 body, global_load_lds;
// V written TRANSPOSED [hd][m] in epilogue; Q pre-scaled by 0.125*log2e),
// (2) causal flash-attention (S^T/O^T, exp2 softmax, BK=64 k-tiles,
// gll16 staging w/ XOR source swizzle), (3) O-proj gemm -> fp32.

#define DMODEL 1024
#define NHEADS 16
#define DHEAD  64
#define SEQ    2048
#define BATCH  2
#define MROWS  (BATCH * SEQ)   // 4096

typedef __bf16 bf16x8 __attribute__((ext_vector_type(8)));
typedef __bf16 bf16x4 __attribute__((ext_vector_type(4)));
typedef float  f32x4  __attribute__((ext_vector_type(4)));

__device__ __forceinline__ f32x4 mfma16(bf16x8 a, bf16x8 b, f32x4 c) {
    return __builtin_amdgcn_mfma_f32_16x16x32_bf16(a, b, c, 0, 0, 0);
}

__device__ __forceinline__ bf16x8 ld8(const float* p) {
    const f32x4 a0 = *(const f32x4*)p;
    const f32x4 a1 = *(const f32x4*)(p + 4);
    bf16x8 v;
    v[0] = (__bf16)a0[0]; v[1] = (__bf16)a0[1];
    v[2] = (__bf16)a0[2]; v[3] = (__bf16)a0[3];
    v[4] = (__bf16)a1[0]; v[5] = (__bf16)a1[1];
    v[6] = (__bf16)a1[2]; v[7] = (__bf16)a1[3];
    return v;
}

// async global->LDS, 16 B/lane; LDS dest = wave-uniform base + lane*16
__device__ __forceinline__ void gll16(const __bf16* g, __bf16* l) {
    __builtin_amdgcn_global_load_lds(
        (const __attribute__((address_space(1))) void*)g,
        (__attribute__((address_space(3))) void*)l,
        16, 0, 0);
}

// ---------------------------------------------------------------------------
// fp32 -> bf16 conversion pass. y=0: x; y=1..4: W's -> wcat.
// ---------------------------------------------------------------------------
__global__ __launch_bounds__(256) void cvt_kernel(const float* __restrict__ x,
                                                  const float* __restrict__ Wq,
                                                  const float* __restrict__ Wk,
                                                  const float* __restrict__ Wv,
                                                  const float* __restrict__ Wo,
                                                  __bf16* __restrict__ xb,
                                                  __bf16* __restrict__ wcat) {
    const int y = blockIdx.y;
    const float* src;
    __bf16* dst;
    int nchunks;
    if (y == 0) { src = x; dst = xb; nchunks = (MROWS * DMODEL) / 8; }
    else {
        src = (y == 1) ? Wq : (y == 2) ? Wk : (y == 3) ? Wv : Wo;
        dst = wcat + (size_t)(y - 1) * DMODEL * DMODEL;
        nchunks = (DMODEL * DMODEL) / 8;
    }
    const int c = blockIdx.x * 256 + threadIdx.x;
    if (c < nchunks) *(bf16x8*)(dst + (size_t)c * 8) = ld8(src + (size_t)c * 8);
}

// ---------------------------------------------------------------------------
// Pure-bf16 GEMM (round-9 structure): BK=32, 128x128 tile, 256 threads,
// global_load_lds w=16 into unpadded LDS. Optional transposed VT epilogue.
// ---------------------------------------------------------------------------
template <typename TC>
__device__ __forceinline__ void gemm_bb_body(const __bf16* __restrict__ A,
                                             const __bf16* __restrict__ W,
                                             TC* __restrict__ C,
                                             __bf16* __restrict__ VT,
                                             bool vt, int m0, int n0,
                                             float scale) {
    constexpr int K = DMODEL;
    __shared__ __align__(16) __bf16 As[128][32];  // NO pad (global_load_lds)
    __shared__ __align__(16) __bf16 Bs[128][32];

    const int tid  = threadIdx.x;
    const int lane = tid & 63;
    const int wave = tid >> 6;
    const int quad = lane >> 4;
    const int l16  = lane & 15;
    const int wm   = wave & 1;
    const int wn   = wave >> 1;

    const int srow = lane >> 2;          // 0..15
    const int scol = (lane & 3) * 8;

    const __bf16* a0p = A + (size_t)(m0 + wave * 16 + srow) * K + scol;
    const __bf16* a1p = A + (size_t)(m0 + 64 + wave * 16 + srow) * K + scol;
    const __bf16* b0p = W + (size_t)(n0 + wave * 16 + srow) * K + scol;
    const __bf16* b1p = W + (size_t)(n0 + 64 + wave * 16 + srow) * K + scol;

    f32x4 acc[4][4] = {};

    for (int k0 = 0; k0 < K; k0 += 32) {
        __syncthreads();
        gll16(a0p + k0, &As[wave * 16][0]);
        gll16(a1p + k0, &As[64 + wave * 16][0]);
        gll16(b0p + k0, &Bs[wave * 16][0]);
        gll16(b1p + k0, &Bs[64 + wave * 16][0]);
        __syncthreads();

        bf16x8 af[4], bfr[4];
#pragma unroll
        for (int i = 0; i < 4; ++i) {
            af[i]  = *(const bf16x8*)(&As[wm * 64 + i * 16 + l16][quad * 8]);
            bfr[i] = *(const bf16x8*)(&Bs[wn * 64 + i * 16 + l16][quad * 8]);
        }
#pragma unroll
        for (int mi = 0; mi < 4; ++mi)
#pragma unroll
            for (int ni = 0; ni < 4; ++ni)
                acc[mi][ni] = mfma16(af[mi], bfr[ni], acc[mi][ni]);
    }

    // C/D layout: col = l16, row = quad*4 + r
    if (!vt) {
#pragma unroll
        for (int mi = 0; mi < 4; ++mi)
#pragma unroll
            for (int ni = 0; ni < 4; ++ni)
#pragma unroll
                for (int r = 0; r < 4; ++r) {
                    int row = m0 + wm * 64 + mi * 16 + quad * 4 + r;
                    int col = n0 + wn * 64 + ni * 16 + l16;
                    C[(size_t)row * DMODEL + col] = (TC)(acc[mi][ni][r] * scale);
                }
    } else {
        // transposed store: VT[hd][m]; lane holds 4 consecutive m -> b64
#pragma unroll
        for (int mi = 0; mi < 4; ++mi)
#pragma unroll
            for (int ni = 0; ni < 4; ++ni) {
                const int m  = m0 + wm * 64 + mi * 16 + quad * 4;
                const int hd = n0 + wn * 64 + ni * 16 + l16;
                bf16x4 v4;
#pragma unroll
                for (int r = 0; r < 4; ++r) v4[r] = (__bf16)acc[mi][ni][r];
                *(bf16x4*)(VT + (size_t)hd * MROWS + m) = v4;
            }
    }
}

// Q pre-scale: 1/sqrt(Dh) * log2(e) so attention scores are log2-domain.
#define QSCALE 0.1803368801111204f

__global__ __launch_bounds__(256) void qkv_kernel(const __bf16* __restrict__ X,
                                                  const __bf16* __restrict__ wcat,
                                                  __bf16* __restrict__ Q,
                                                  __bf16* __restrict__ K,
                                                  __bf16* __restrict__ VT) {
    const int z = blockIdx.z;
    const __bf16* W = wcat + (size_t)z * DMODEL * DMODEL;
    __bf16* Y = (z == 0) ? Q : K;   // z==2 uses VT path
    const float scale = (z == 0) ? QSCALE : 1.0f;
    gemm_bb_body<__bf16>(X, W, Y, VT, z == 2,
                         blockIdx.y * 128, blockIdx.x * 128, scale);
}

__global__ __launch_bounds__(256) void out_gemm_kernel(const __bf16* __restrict__ A,
                                                       const __bf16* __restrict__ W,
                                                       float* __restrict__ C) {
    gemm_bb_body<float>(A, W, C, nullptr, false,
                        blockIdx.y * 128, blockIdx.x * 128, 1.0f);
}

// ---------------------------------------------------------------------------
// Causal flash attention, S^T / O^T, exp2 softmax, BK=64 k-tiles.
// Block = 128 threads (2 waves x 16 q). Grid (bh 32, y 64), qt = 63-y.
// K staged [kk 64][d 64], V^T staged [dh 64][kk 64], both via gll16 with XOR
// source swizzle (granule ^= row&7) -> b128 fragment reads 2-way (free).
// ntiles = qt/2+1; only the last tile applies the causal mask.
// Per iteration: 8 S-MFMAs + 8 PV-MFMAs, ONE reduce/alpha (vs two at BK=32).
// ---------------------------------------------------------------------------
__global__ __launch_bounds__(128) void attn_kernel(const __bf16* __restrict__ Q,
                                                   const __bf16* __restrict__ Kg,
                                                   const __bf16* __restrict__ VTg,
                                                   __bf16* __restrict__ O) {
    const int bh = blockIdx.x;        // 0..31 (fast dim -> XCD affinity)
    const int qt = 63 - blockIdx.y;   // 0..63, biggest tiles first
    const int b = bh >> 4, h = bh & 15;
    const size_t base = (size_t)b * SEQ * DMODEL + (size_t)h * DHEAD;

    const int tid  = threadIdx.x;
    const int lane = tid & 63;
    const int wave = tid >> 6;
    const int quad = lane >> 4;
    const int l16  = lane & 15;

    __shared__ __align__(16) __bf16 Ks[64][64];        // [kk][d], swizzled
    __shared__ __align__(16) __bf16 Vs[64][64];        // [dh][kk], swizzled
    __shared__ __align__(16) __bf16 Ps[2][2][16][40];  // [wave][kk-half][q][kk32]

    // gll16 staging: lane l covers row_local l>>3, src granule (l&7)^(l>>3)
    const int sr = lane >> 3;                 // 0..7
    const int sc = ((lane & 7) ^ sr) * 8;

    const int qrow = qt * 32 + wave * 16 + l16;

    // Q fragments (already scaled by 0.125*log2e at QKV epilogue)
    const bf16x8 qf0 = *(const bf16x8*)(Q + base + (size_t)qrow * DMODEL + quad * 8);
    const bf16x8 qf1 = *(const bf16x8*)(Q + base + (size_t)qrow * DMODEL + 32 + quad * 8);

    f32x4 oacc[4] = {};
    float m_i = -1e30f, l_i = 0.f;

    const int ntiles = (qt >> 1) + 1;
    const int gsw = (l16 & 7);   // read-side swizzle term

    for (int kt = 0; kt < ntiles; ++kt) {
        const int k0 = kt * 64;
        __syncthreads();   // previous tile's reads done
#pragma unroll
        for (int j = 0; j < 4; ++j) {
            const int row = wave * 32 + j * 8;
            gll16(Kg + base + (size_t)(k0 + row + sr) * DMODEL + sc, &Ks[row][0]);
            gll16(VTg + (size_t)(h * 64 + row + sr) * MROWS + (size_t)b * SEQ + k0 + sc,
                  &Vs[row][0]);
        }
        __syncthreads();   // vmcnt drained before LDS reads

        const bool diag = (kt == ntiles - 1);   // wave-uniform

        // S^T[kk][q] (log2 domain): 4 kk-groups x 2 d-halves
        f32x4 s[4];
#pragma unroll
        for (int g = 0; g < 4; ++g) {
            const bf16x8 kfa = *(const bf16x8*)(&Ks[g * 16 + l16][(quad ^ gsw) * 8]);
            const bf16x8 kfb = *(const bf16x8*)(&Ks[g * 16 + l16][((quad + 4) ^ gsw) * 8]);
            f32x4 t = {};
            t = mfma16(kfa, qf0, t);
            t = mfma16(kfb, qf1, t);
            s[g] = t;
        }

        float mx;
        bool ok[4][4];
        if (!diag) {
            mx = s[0][0];
#pragma unroll
            for (int g = 0; g < 4; ++g)
#pragma unroll
                for (int r = 0; r < 4; ++r) mx = fmaxf(mx, s[g][r]);
        } else {
            mx = -1e30f;
#pragma unroll
            for (int g = 0; g < 4; ++g)
#pragma unroll
                for (int r = 0; r < 4; ++r) {
                    const int kk = k0 + g * 16 + quad * 4 + r;
                    ok[g][r] = (kk <= qrow);
                    mx = fmaxf(mx, ok[g][r] ? s[g][r] : -1e30f);
                }
        }
        mx = fmaxf(mx, __shfl_xor(mx, 16));
        mx = fmaxf(mx, __shfl_xor(mx, 32));
        const float mnew  = fmaxf(m_i, mx);
        const float alpha = exp2f(m_i - mnew);
        m_i = mnew;

        float rs = 0.f;
        bf16x4 w4[4];
        if (!diag) {
#pragma unroll
            for (int g = 0; g < 4; ++g)
#pragma unroll
                for (int r = 0; r < 4; ++r) {
                    const float p = exp2f(s[g][r] - mnew);
                    rs += p;
                    w4[g][r] = (__bf16)p;
                }
        } else {
#pragma unroll
            for (int g = 0; g < 4; ++g)
#pragma unroll
                for (int r = 0; r < 4; ++r) {
                    const float p = ok[g][r] ? exp2f(s[g][r] - mnew) : 0.f;
                    rs += p;
                    w4[g][r] = (__bf16)p;
                }
        }
        rs += __shfl_xor(rs, 16);
        rs += __shfl_xor(rs, 32);
        l_i = l_i * alpha + rs;

        // P^T -> LDS (wave-private halves): kk = g*16+quad*4+r
#pragma unroll
        for (int g = 0; g < 4; ++g)
            *(bf16x4*)(&Ps[wave][g >> 1][l16][(g & 1) * 16 + quad * 4]) = w4[g];

        // O^T += V^T P^T : two kk-halves
        const bf16x8 pf0 = *(const bf16x8*)(&Ps[wave][0][l16][quad * 8]);
        const bf16x8 pf1 = *(const bf16x8*)(&Ps[wave][1][l16][quad * 8]);
#pragma unroll
        for (int f = 0; f < 4; ++f) {
            const bf16x8 vfa = *(const bf16x8*)(&Vs[f * 16 + l16][(quad ^ gsw) * 8]);
            const bf16x8 vfb = *(const bf16x8*)(&Vs[f * 16 + l16][((quad + 4) ^ gsw) * 8]);
            f32x4 t = oacc[f] * alpha;
            t = mfma16(vfa, pf0, t);
            t = mfma16(vfb, pf1, t);
            oacc[f] = t;
        }
    }

    const float inv = (l_i > 0.f) ? (1.f / l_i) : 0.f;
#pragma unroll
    for (int f = 0; f < 4; ++f) {
        bf16x4 o;
#pragma unroll
        for (int r = 0; r < 4; ++r) o[r] = (__bf16)(oacc[f][r] * inv);
        *(bf16x4*)(O + base + (size_t)qrow * DMODEL + f * 16 + quad * 4) = o;
    }
}

// ---------------------------------------------------------------------------
extern "C" void kernel_launch(void* const* d_in, const int* in_sizes, int n_in,
                              void* d_out, int out_size, void* d_ws, size_t ws_size,
                              hipStream_t stream) {
    const float* x  = (const float*)d_in[0];
    const float* Wq = (const float*)d_in[1];
    const float* Wk = (const float*)d_in[2];
    const float* Wv = (const float*)d_in[3];
    const float* Wo = (const float*)d_in[4];
    float* out = (float*)d_out;

    const size_t tm = (size_t)MROWS * DMODEL;    // 4M elems
    const size_t tw = (size_t)DMODEL * DMODEL;   // 1M elems
    __bf16* Q    = (__bf16*)d_ws;                // 4M
    __bf16* K    = Q + tm;                       // 4M
    __bf16* VT   = K + tm;                       // 4M  (V transposed [hd][m])
    __bf16* xb   = VT + tm;                      // 4M
    __bf16* wcat = xb + tm;                      // 4M (Wq,Wk,Wv,Wo)  -> 40 MB

    dim3 gc(2048, 5);
    cvt_kernel<<<gc, 256, 0, stream>>>(x, Wq, Wk, Wv, Wo, xb, wcat);

    dim3 g1(DMODEL / 128, MROWS / 128, 3);
    qkv_kernel<<<g1, 256, 0, stream>>>(xb, wcat, Q, K, VT);

    dim3 g2(BATCH * NHEADS, SEQ / 32);           // (bh, y): qt = 63 - y
    attn_kernel<<<g2, 128, 0, stream>>>(Q, K, VT, /*O=*/Q);

    dim3 g3(DMODEL / 128, MROWS / 128);
    out_gemm_kernel<<<g3, 256, 0, stream>>>(/*O=*/Q, wcat + 3 * tw, out);
}

// Round 12
// 190.892 us; speedup vs baseline: 1.1392x; 1.0188x over previous
//
#include <hip/hip_runtime.h>

// MHA forward: inputs fp32, output fp32. Internals bf16 MFMA.
// (0) cvt fp32->bf16, (1) QKV gemm (BK=32 m97-style, global_load_lds;
// V written TRANSPOSED [hd][m]; Q pre-scaled by 0.125*log2e),
// (2) causal flash-attention (S^T/O^T, exp2 softmax, BK=64, 256-thread
// blocks: 4 waves share one K/V tile), (3) O-proj gemm -> fp32.

#define DMODEL 1024
#define NHEADS 16
#define DHEAD  64
#define SEQ    2048
#define BATCH  2
#define MROWS  (BATCH * SEQ)   // 4096

typedef __bf16 bf16x8 __attribute__((ext_vector_type(8)));
typedef __bf16 bf16x4 __attribute__((ext_vector_type(4)));
typedef float  f32x4  __attribute__((ext_vector_type(4)));

__device__ __forceinline__ f32x4 mfma16(bf16x8 a, bf16x8 b, f32x4 c) {
    return __builtin_amdgcn_mfma_f32_16x16x32_bf16(a, b, c, 0, 0, 0);
}

__device__ __forceinline__ bf16x8 ld8(const float* p) {
    const f32x4 a0 = *(const f32x4*)p;
    const f32x4 a1 = *(const f32x4*)(p + 4);
    bf16x8 v;
    v[0] = (__bf16)a0[0]; v[1] = (__bf16)a0[1];
    v[2] = (__bf16)a0[2]; v[3] = (__bf16)a0[3];
    v[4] = (__bf16)a1[0]; v[5] = (__bf16)a1[1];
    v[6] = (__bf16)a1[2]; v[7] = (__bf16)a1[3];
    return v;
}

// async global->LDS, 16 B/lane; LDS dest = wave-uniform base + lane*16
__device__ __forceinline__ void gll16(const __bf16* g, __bf16* l) {
    __builtin_amdgcn_global_load_lds(
        (const __attribute__((address_space(1))) void*)g,
        (__attribute__((address_space(3))) void*)l,
        16, 0, 0);
}

// ---------------------------------------------------------------------------
// fp32 -> bf16 conversion pass. y=0: x; y=1..4: W's -> wcat.
// ---------------------------------------------------------------------------
__global__ __launch_bounds__(256) void cvt_kernel(const float* __restrict__ x,
                                                  const float* __restrict__ Wq,
                                                  const float* __restrict__ Wk,
                                                  const float* __restrict__ Wv,
                                                  const float* __restrict__ Wo,
                                                  __bf16* __restrict__ xb,
                                                  __bf16* __restrict__ wcat) {
    const int y = blockIdx.y;
    const float* src;
    __bf16* dst;
    int nchunks;
    if (y == 0) { src = x; dst = xb; nchunks = (MROWS * DMODEL) / 8; }
    else {
        src = (y == 1) ? Wq : (y == 2) ? Wk : (y == 3) ? Wv : Wo;
        dst = wcat + (size_t)(y - 1) * DMODEL * DMODEL;
        nchunks = (DMODEL * DMODEL) / 8;
    }
    const int c = blockIdx.x * 256 + threadIdx.x;
    if (c < nchunks) *(bf16x8*)(dst + (size_t)c * 8) = ld8(src + (size_t)c * 8);
}

// ---------------------------------------------------------------------------
// Pure-bf16 GEMM (round-9 structure): BK=32, 128x128 tile, 256 threads,
// global_load_lds w=16 into unpadded LDS. Optional transposed VT epilogue.
// ---------------------------------------------------------------------------
template <typename TC>
__device__ __forceinline__ void gemm_bb_body(const __bf16* __restrict__ A,
                                             const __bf16* __restrict__ W,
                                             TC* __restrict__ C,
                                             __bf16* __restrict__ VT,
                                             bool vt, int m0, int n0,
                                             float scale) {
    constexpr int K = DMODEL;
    __shared__ __align__(16) __bf16 As[128][32];  // NO pad (global_load_lds)
    __shared__ __align__(16) __bf16 Bs[128][32];

    const int tid  = threadIdx.x;
    const int lane = tid & 63;
    const int wave = tid >> 6;
    const int quad = lane >> 4;
    const int l16  = lane & 15;
    const int wm   = wave & 1;
    const int wn   = wave >> 1;

    const int srow = lane >> 2;          // 0..15
    const int scol = (lane & 3) * 8;

    const __bf16* a0p = A + (size_t)(m0 + wave * 16 + srow) * K + scol;
    const __bf16* a1p = A + (size_t)(m0 + 64 + wave * 16 + srow) * K + scol;
    const __bf16* b0p = W + (size_t)(n0 + wave * 16 + srow) * K + scol;
    const __bf16* b1p = W + (size_t)(n0 + 64 + wave * 16 + srow) * K + scol;

    f32x4 acc[4][4] = {};

    for (int k0 = 0; k0 < K; k0 += 32) {
        __syncthreads();
        gll16(a0p + k0, &As[wave * 16][0]);
        gll16(a1p + k0, &As[64 + wave * 16][0]);
        gll16(b0p + k0, &Bs[wave * 16][0]);
        gll16(b1p + k0, &Bs[64 + wave * 16][0]);
        __syncthreads();

        bf16x8 af[4], bfr[4];
#pragma unroll
        for (int i = 0; i < 4; ++i) {
            af[i]  = *(const bf16x8*)(&As[wm * 64 + i * 16 + l16][quad * 8]);
            bfr[i] = *(const bf16x8*)(&Bs[wn * 64 + i * 16 + l16][quad * 8]);
        }
#pragma unroll
        for (int mi = 0; mi < 4; ++mi)
#pragma unroll
            for (int ni = 0; ni < 4; ++ni)
                acc[mi][ni] = mfma16(af[mi], bfr[ni], acc[mi][ni]);
    }

    // C/D layout: col = l16, row = quad*4 + r
    if (!vt) {
#pragma unroll
        for (int mi = 0; mi < 4; ++mi)
#pragma unroll
            for (int ni = 0; ni < 4; ++ni)
#pragma unroll
                for (int r = 0; r < 4; ++r) {
                    int row = m0 + wm * 64 + mi * 16 + quad * 4 + r;
                    int col = n0 + wn * 64 + ni * 16 + l16;
                    C[(size_t)row * DMODEL + col] = (TC)(acc[mi][ni][r] * scale);
                }
    } else {
        // transposed store: VT[hd][m]; lane holds 4 consecutive m -> b64
#pragma unroll
        for (int mi = 0; mi < 4; ++mi)
#pragma unroll
            for (int ni = 0; ni < 4; ++ni) {
                const int m  = m0 + wm * 64 + mi * 16 + quad * 4;
                const int hd = n0 + wn * 64 + ni * 16 + l16;
                bf16x4 v4;
#pragma unroll
                for (int r = 0; r < 4; ++r) v4[r] = (__bf16)acc[mi][ni][r];
                *(bf16x4*)(VT + (size_t)hd * MROWS + m) = v4;
            }
    }
}

// Q pre-scale: 1/sqrt(Dh) * log2(e) so attention scores are log2-domain.
#define QSCALE 0.1803368801111204f

__global__ __launch_bounds__(256) void qkv_kernel(const __bf16* __restrict__ X,
                                                  const __bf16* __restrict__ wcat,
                                                  __bf16* __restrict__ Q,
                                                  __bf16* __restrict__ K,
                                                  __bf16* __restrict__ VT) {
    const int z = blockIdx.z;
    const __bf16* W = wcat + (size_t)z * DMODEL * DMODEL;
    __bf16* Y = (z == 0) ? Q : K;   // z==2 uses VT path
    const float scale = (z == 0) ? QSCALE : 1.0f;
    gemm_bb_body<__bf16>(X, W, Y, VT, z == 2,
                         blockIdx.y * 128, blockIdx.x * 128, scale);
}

__global__ __launch_bounds__(256) void out_gemm_kernel(const __bf16* __restrict__ A,
                                                       const __bf16* __restrict__ W,
                                                       float* __restrict__ C) {
    gemm_bb_body<float>(A, W, C, nullptr, false,
                        blockIdx.y * 128, blockIdx.x * 128, 1.0f);
}

// ---------------------------------------------------------------------------
// Causal flash attention, S^T / O^T, exp2 softmax, BK=64 k-tiles.
// Block = 256 threads: 4 waves x 16 q-rows = 64-row q-tile SHARING one K/V
// stage (halves staging work per wave vs 2-wave blocks). Grid (bh 32, y 32),
// qt2 = 31-y (big first); co-resident blocks differ in y by 8 -> balanced.
// 1024 blocks = 4/CU x 8 waves = 32 waves/CU occupancy cap (was 27% meas.).
// K staged [kk 64][d 64], V^T staged [dh 64][kk 64] via gll16 + XOR swizzle.
// Only the last k-tile applies the causal mask.
// ---------------------------------------------------------------------------
__global__ __launch_bounds__(256) void attn_kernel(const __bf16* __restrict__ Q,
                                                   const __bf16* __restrict__ Kg,
                                                   const __bf16* __restrict__ VTg,
                                                   __bf16* __restrict__ O) {
    const int bh  = blockIdx.x;        // 0..31 (fast dim -> XCD affinity)
    const int qt2 = 31 - blockIdx.y;   // 0..31, 64-row q-tile, biggest first
    const int b = bh >> 4, h = bh & 15;
    const size_t base = (size_t)b * SEQ * DMODEL + (size_t)h * DHEAD;

    const int tid  = threadIdx.x;
    const int lane = tid & 63;
    const int wave = tid >> 6;   // 0..3
    const int quad = lane >> 4;
    const int l16  = lane & 15;

    __shared__ __align__(16) __bf16 Ks[64][64];        // [kk][d], swizzled
    __shared__ __align__(16) __bf16 Vs[64][64];        // [dh][kk], swizzled
    __shared__ __align__(16) __bf16 Ps[4][2][16][40];  // [wave][kk-half][q][kk32]

    // gll16 staging: lane l covers row_local l>>3, src granule (l&7)^(l>>3)
    const int sr = lane >> 3;                 // 0..7
    const int sc = ((lane & 7) ^ sr) * 8;

    const int qrow = qt2 * 64 + wave * 16 + l16;

    // Q fragments (already scaled by 0.125*log2e at QKV epilogue)
    const bf16x8 qf0 = *(const bf16x8*)(Q + base + (size_t)qrow * DMODEL + quad * 8);
    const bf16x8 qf1 = *(const bf16x8*)(Q + base + (size_t)qrow * DMODEL + 32 + quad * 8);

    f32x4 oacc[4] = {};
    float m_i = -1e30f, l_i = 0.f;

    const int ntiles = qt2 + 1;
    const int gsw = (l16 & 7);   // read-side swizzle term

    for (int kt = 0; kt < ntiles; ++kt) {
        const int k0 = kt * 64;
        __syncthreads();   // previous tile's reads done
#pragma unroll
        for (int j = 0; j < 2; ++j) {
            const int row = wave * 16 + j * 8;   // 4 waves cover 64 rows
            gll16(Kg + base + (size_t)(k0 + row + sr) * DMODEL + sc, &Ks[row][0]);
            gll16(VTg + (size_t)(h * 64 + row + sr) * MROWS + (size_t)b * SEQ + k0 + sc,
                  &Vs[row][0]);
        }
        __syncthreads();   // vmcnt drained before LDS reads

        const bool diag = (kt == ntiles - 1);   // block-uniform

        // S^T[kk][q] (log2 domain): 4 kk-groups x 2 d-halves
        f32x4 s[4];
#pragma unroll
        for (int g = 0; g < 4; ++g) {
            const bf16x8 kfa = *(const bf16x8*)(&Ks[g * 16 + l16][(quad ^ gsw) * 8]);
            const bf16x8 kfb = *(const bf16x8*)(&Ks[g * 16 + l16][((quad + 4) ^ gsw) * 8]);
            f32x4 t = {};
            t = mfma16(kfa, qf0, t);
            t = mfma16(kfb, qf1, t);
            s[g] = t;
        }

        float mx;
        bool ok[4][4];
        if (!diag) {
            mx = s[0][0];
#pragma unroll
            for (int g = 0; g < 4; ++g)
#pragma unroll
                for (int r = 0; r < 4; ++r) mx = fmaxf(mx, s[g][r]);
        } else {
            mx = -1e30f;
#pragma unroll
            for (int g = 0; g < 4; ++g)
#pragma unroll
                for (int r = 0; r < 4; ++r) {
                    const int kk = k0 + g * 16 + quad * 4 + r;
                    ok[g][r] = (kk <= qrow);
                    mx = fmaxf(mx, ok[g][r] ? s[g][r] : -1e30f);
                }
        }
        mx = fmaxf(mx, __shfl_xor(mx, 16));
        mx = fmaxf(mx, __shfl_xor(mx, 32));
        const float mnew  = fmaxf(m_i, mx);
        const float alpha = exp2f(m_i - mnew);
        m_i = mnew;

        float rs = 0.f;
        bf16x4 w4[4];
        if (!diag) {
#pragma unroll
            for (int g = 0; g < 4; ++g)
#pragma unroll
                for (int r = 0; r < 4; ++r) {
                    const float p = exp2f(s[g][r] - mnew);
                    rs += p;
                    w4[g][r] = (__bf16)p;
                }
        } else {
#pragma unroll
            for (int g = 0; g < 4; ++g)
#pragma unroll
                for (int r = 0; r < 4; ++r) {
                    const float p = ok[g][r] ? exp2f(s[g][r] - mnew) : 0.f;
                    rs += p;
                    w4[g][r] = (__bf16)p;
                }
        }
        rs += __shfl_xor(rs, 16);
        rs += __shfl_xor(rs, 32);
        l_i = l_i * alpha + rs;

        // P^T -> LDS (wave-private halves): kk = g*16+quad*4+r
#pragma unroll
        for (int g = 0; g < 4; ++g)
            *(bf16x4*)(&Ps[wave][g >> 1][l16][(g & 1) * 16 + quad * 4]) = w4[g];

        // O^T += V^T P^T : two kk-halves
        const bf16x8 pf0 = *(const bf16x8*)(&Ps[wave][0][l16][quad * 8]);
        const bf16x8 pf1 = *(const bf16x8*)(&Ps[wave][1][l16][quad * 8]);
#pragma unroll
        for (int f = 0; f < 4; ++f) {
            const bf16x8 vfa = *(const bf16x8*)(&Vs[f * 16 + l16][(quad ^ gsw) * 8]);
            const bf16x8 vfb = *(const bf16x8*)(&Vs[f * 16 + l16][((quad + 4) ^ gsw) * 8]);
            f32x4 t = oacc[f] * alpha;
            t = mfma16(vfa, pf0, t);
            t = mfma16(vfb, pf1, t);
            oacc[f] = t;
        }
    }

    const float inv = (l_i > 0.f) ? (1.f / l_i) : 0.f;
#pragma unroll
    for (int f = 0; f < 4; ++f) {
        bf16x4 o;
#pragma unroll
        for (int r = 0; r < 4; ++r) o[r] = (__bf16)(oacc[f][r] * inv);
        *(bf16x4*)(O + base + (size_t)qrow * DMODEL + f * 16 + quad * 4) = o;
    }
}

// ---------------------------------------------------------------------------
extern "C" void kernel_launch(void* const* d_in, const int* in_sizes, int n_in,
                              void* d_out, int out_size, void* d_ws, size_t ws_size,
                              hipStream_t stream) {
    const float* x  = (const float*)d_in[0];
    const float* Wq = (const float*)d_in[1];
    const float* Wk = (const float*)d_in[2];
    const float* Wv = (const float*)d_in[3];
    const float* Wo = (const float*)d_in[4];
    float* out = (float*)d_out;

    const size_t tm = (size_t)MROWS * DMODEL;    // 4M elems
    const size_t tw = (size_t)DMODEL * DMODEL;   // 1M elems
    __bf16* Q    = (__bf16*)d_ws;                // 4M
    __bf16* K    = Q + tm;                       // 4M
    __bf16* VT   = K + tm;                       // 4M  (V transposed [hd][m])
    __bf16* xb   = VT + tm;                      // 4M
    __bf16* wcat = xb + tm;                      // 4M (Wq,Wk,Wv,Wo)  -> 40 MB

    dim3 gc(2048, 5);
    cvt_kernel<<<gc, 256, 0, stream>>>(x, Wq, Wk, Wv, Wo, xb, wcat);

    dim3 g1(DMODEL / 128, MROWS / 128, 3);
    qkv_kernel<<<g1, 256, 0, stream>>>(xb, wcat, Q, K, VT);

    dim3 g2(BATCH * NHEADS, SEQ / 64);           // (bh, y): qt2 = 31 - y
    attn_kernel<<<g2, 256, 0, stream>>>(Q, K, VT, /*O=*/Q);

    dim3 g3(DMODEL / 128, MROWS / 128);
    out_gemm_kernel<<<g3, 256, 0, stream>>>(/*O=*/Q, wcat + 3 * tw, out);
}